// Round 4
// baseline (339.991 us; speedup 1.0000x reference)
//
#include <hip/hip_runtime.h>
#include <float.h>
#include <math.h>

#define NB 16
#define NN 577
#define NC 384
#define NH 6
#define ND 64
#define RPD2 2209
#define MTOT 9232
#define MPAD 9344
#define SCALE_ 0.125f
#define NEGBIG -3.0e38f
#define BSTRIDE 580
#define NKPAD 640

typedef __attribute__((ext_vector_type(8))) short bf16x8;
typedef __attribute__((ext_vector_type(4))) float f32x4;
typedef unsigned short u16;

#define MFMA16(a, b, c) __builtin_amdgcn_mfma_f32_16x16x32_bf16(a, b, c, 0, 0, 0)

// workspace offsets in u16 units
#define SQA 3932160ull                    // 96*640*64
#define OFF_QH 0ull
#define OFF_QL SQA
#define OFF_KH (2ull * SQA)
#define OFF_KL (3ull * SQA)
#define OFF_VTH (4ull * SQA)
#define OFF_VTL (5ull * SQA)
#define OFF_XH (6ull * SQA)               // aliased as Oh after qkv
#define OFF_XL (6ull * SQA + 3588096ull)  // aliased as Ol
#define OFF_WQH (6ull * SQA + 2ull * 3588096ull)
#define OFF_WQL (OFF_WQH + 442368ull)
#define OFF_WPH (OFF_WQL + 442368ull)
#define OFF_WPL (OFF_WPH + 147456ull)
#define OFF_BT  (OFF_WPL + 147456ull)
#define OFF_PM  (OFF_BT + 2007960ull)     // u32 region, 8B-aligned

static __device__ __forceinline__ u16 f2bf(float f) {
  unsigned u = __float_as_uint(f);
  u += 0x7fff + ((u >> 16) & 1);
  return (u16)(u >> 16);
}
static __device__ __forceinline__ float bf2f(u16 h) {
  return __uint_as_float((unsigned)h << 16);
}
static __device__ __forceinline__ void split2(float v, u16& hi, u16& lo) {
  hi = f2bf(v);
  lo = f2bf(v - bf2f(hi));
}

// ---------------------------------------------------------------------------
// Split fp32 inputs (x padded to 9344 rows with zeros, qkv_w, proj_w) into
// bf16 hi/lo pairs. One float4 quad per thread; grid = 4080 blocks exactly.
// ---------------------------------------------------------------------------
__global__ __launch_bounds__(256) void split_inputs_k(
    const float* __restrict__ x, const float* __restrict__ wq,
    const float* __restrict__ wp, u16* __restrict__ ws)
{
  const int q = blockIdx.x * 256 + threadIdx.x;
  float4 v = {0.f, 0.f, 0.f, 0.f};
  u16 *dh, *dl;
  if (q < 897024) {                       // X region (incl zero pad rows)
    if (q < 886272) v = ((const float4*)x)[q];
    dh = ws + OFF_XH + 4ull * q;
    dl = ws + OFF_XL + 4ull * q;
  } else if (q < 1007616) {               // qkv_w
    int t = q - 897024;
    v = ((const float4*)wq)[t];
    dh = ws + OFF_WQH + 4ull * t;
    dl = ws + OFF_WQL + 4ull * t;
  } else {                                // proj_w
    int t = q - 1007616;
    v = ((const float4*)wp)[t];
    dh = ws + OFF_WPH + 4ull * t;
    dl = ws + OFF_WPL + 4ull * t;
  }
  ushort4 hh, ll;
  split2(v.x, hh.x, ll.x);
  split2(v.y, hh.y, ll.y);
  split2(v.z, hh.z, ll.z);
  split2(v.w, hh.w, ll.w);
  *(ushort4*)dh = hh;
  *(ushort4*)dl = ll;
}

// ---------------------------------------------------------------------------
// Pack mask int32 -> bitmask.
// ---------------------------------------------------------------------------
__global__ __launch_bounds__(256) void pack_mask_k(const int* __restrict__ mask,
                                                   unsigned* __restrict__ pm)
{
  const int wid = (blockIdx.x * 256 + threadIdx.x) >> 6;
  const int lane = threadIdx.x & 63;
  if (wid >= MTOT) return;
  const int* mr = mask + (size_t)wid * NN;
#pragma unroll
  for (int c = 0; c < 10; ++c) {
    int k = c * 64 + lane;
    int v = (k < NN) ? mr[k] : 0;
    unsigned long long bal = __ballot(v != 0);
    if (lane == 0) pm[wid * 20 + 2 * c] = (unsigned)bal;
    if (lane == 1) pm[wid * 20 + 2 * c + 1] = (unsigned)(bal >> 32);
  }
}

// ---------------------------------------------------------------------------
// Bias table: tbl[h][q][kk] = rel_pos[h][rel_idx[(q-1)*576 + kk-1]] bf16.
// ---------------------------------------------------------------------------
__global__ __launch_bounds__(256) void bias_build_k(
    const float* __restrict__ rel_pos, const int* __restrict__ rel_idx,
    const int* __restrict__ patch, u16* __restrict__ tbl)
{
  const int q = blockIdx.x;
  const int h = blockIdx.y;
  const int pa = *patch;
  u16* row = tbl + ((size_t)h * NN + q) * BSTRIDE;
  for (int kk = threadIdx.x; kk < BSTRIDE; kk += 256) {
    float v = 0.f;
    if (pa && q >= 1 && kk >= 1 && kk < NN)
      v = rel_pos[h * RPD2 + rel_idx[(q - 1) * 576 + (kk - 1)]];
    row[kk] = f2bf(v);
  }
}

// ---------------------------------------------------------------------------
// QKV GEMM, split-bf16 MFMA, LDS-free (fragments direct from global).
// Block 256 thr = 4 waves (2x2), wave tile 64x64, block tile 128x128.
// Epilogue scatters Q (scaled, split), K (split), V (split, transposed).
// ---------------------------------------------------------------------------
__global__ __launch_bounds__(256, 2) void qkv_mfma_k(
    const u16* __restrict__ Xh, const u16* __restrict__ Xl,
    const u16* __restrict__ Wh, const u16* __restrict__ Wl,
    const float* __restrict__ bias, u16* __restrict__ ws)
{
  const int tid = threadIdx.x;
  const int w = tid >> 6, l = tid & 63, lq = l & 15, lg = l >> 4;
  const int wm = (w >> 1) * 64, wn = (w & 1) * 64;
  const int m0 = blockIdx.x * 128 + wm;
  const int rb = blockIdx.y * 128;
  const int r0 = rb + wn;

  f32x4 acc[4][4];
#pragma unroll
  for (int nt = 0; nt < 4; ++nt) {
    float bv = bias[r0 + 16 * nt + lq];
#pragma unroll
    for (int mt = 0; mt < 4; ++mt) acc[mt][nt] = (f32x4){bv, bv, bv, bv};
  }

  const size_t arow = (size_t)(m0 + lq) * 384 + 8 * lg;
  const size_t brow = (size_t)(r0 + lq) * 384 + 8 * lg;
  for (int k0 = 0; k0 < 384; k0 += 32) {
    bf16x8 ah[4], al[4], bh_[4], bl_[4];
#pragma unroll
    for (int mt = 0; mt < 4; ++mt) {
      ah[mt] = *(const bf16x8*)&Xh[arow + (size_t)(16 * mt) * 384 + k0];
      al[mt] = *(const bf16x8*)&Xl[arow + (size_t)(16 * mt) * 384 + k0];
    }
#pragma unroll
    for (int nt = 0; nt < 4; ++nt) {
      bh_[nt] = *(const bf16x8*)&Wh[brow + (size_t)(16 * nt) * 384 + k0];
      bl_[nt] = *(const bf16x8*)&Wl[brow + (size_t)(16 * nt) * 384 + k0];
    }
#pragma unroll
    for (int mt = 0; mt < 4; ++mt)
#pragma unroll
      for (int nt = 0; nt < 4; ++nt) {
        acc[mt][nt] = MFMA16(ah[mt], bh_[nt], acc[mt][nt]);
        acc[mt][nt] = MFMA16(ah[mt], bl_[nt], acc[mt][nt]);
        acc[mt][nt] = MFMA16(al[mt], bh_[nt], acc[mt][nt]);
      }
  }

  const int comp = rb / 384;                 // 0=Q 1=K 2=V (block-uniform)
  const int h = ((rb % 384) + wn) >> 6;
#pragma unroll
  for (int mt = 0; mt < 4; ++mt)
#pragma unroll
    for (int r = 0; r < 4; ++r) {
      int m = m0 + 16 * mt + 4 * lg + r;
      if (m >= MTOT) continue;
      int bb = m / NN, nn = m - bb * NN;
      int bh = bb * NH + h;
#pragma unroll
      for (int nt = 0; nt < 4; ++nt) {
        int d = 16 * nt + lq;
        float v = acc[mt][nt][r];
        u16 hi, lo;
        if (comp == 0) {
          v *= SCALE_;
          split2(v, hi, lo);
          size_t a = ((size_t)bh * NKPAD + nn) * 64 + d;
          ws[OFF_QH + a] = hi;
          ws[OFF_QL + a] = lo;
        } else if (comp == 1) {
          split2(v, hi, lo);
          size_t a = ((size_t)bh * NKPAD + nn) * 64 + d;
          ws[OFF_KH + a] = hi;
          ws[OFF_KL + a] = lo;
        } else {
          split2(v, hi, lo);
          size_t a = ((size_t)bh * 64 + d) * NKPAD + nn;
          ws[OFF_VTH + a] = hi;
          ws[OFF_VTL + a] = lo;
        }
      }
    }
}

// ---------------------------------------------------------------------------
// Flash attention v3: no staging LDS, no __syncthreads. Fragments direct
// from pre-split global Q/K/Vt. LDS only for per-wave P repack (swizzled).
// Writes O as split bf16 in (B,N,C) layout to feed proj directly.
// ---------------------------------------------------------------------------
__global__ __launch_bounds__(256, 3) void attn_k(
    const u16* __restrict__ Qh, const u16* __restrict__ Ql,
    const u16* __restrict__ Kh, const u16* __restrict__ Kl,
    const u16* __restrict__ Vth, const u16* __restrict__ Vtl,
    const u16* __restrict__ btbl, const unsigned* __restrict__ pm,
    u16* __restrict__ Oh, u16* __restrict__ Ol)
{
  __shared__ u16 Ph[4][1024];   // per-wave [16][64] swizzled
  __shared__ u16 Pl[4][1024];

  const int tid = threadIdx.x;
  const int w = tid >> 6, l = tid & 63, lq = l & 15, lg = l >> 4;
  const int q0 = blockIdx.x * 64;
  const int h = blockIdx.y, b = blockIdx.z;
  const int bh = b * NH + h;
  const int qrow = q0 + 16 * w + lq;
  const int sw = (lq & 7) << 3;

  // Q fragments (persistent)
  const size_t qbase = ((size_t)bh * NKPAD + qrow) * 64 + 8 * lg;
  bf16x8 qbh[2], qbl[2];
  qbh[0] = *(const bf16x8*)&Qh[qbase];
  qbh[1] = *(const bf16x8*)&Qh[qbase + 32];
  qbl[0] = *(const bf16x8*)&Ql[qbase];
  qbl[1] = *(const bf16x8*)&Ql[qbase + 32];

  const bool qv = qrow < NN;
  const int gqc = qv ? qrow : NN - 1;
  const unsigned* pmrow = pm + ((size_t)b * NN + gqc) * 20;
  const size_t brow = ((size_t)h * NN + gqc) * BSTRIDE;

  float m_reg = NEGBIG, l_reg = 0.f;
  f32x4 accO[4] = {};

  for (int ch = 0; ch < 10; ++ch) {
    const int kb = ch * 64;
    unsigned long long m64 = (unsigned long long)pmrow[2 * ch] |
                             ((unsigned long long)pmrow[2 * ch + 1] << 32);

    // ---- S^T = K*Q^T, bias via C-init ----
    float sv[4][4];
#pragma unroll
    for (int t = 0; t < 4; ++t) {
      f32x4 acc = {};
      int kkb = kb + 16 * t + 4 * lg;
      if (qv && kkb <= 576) {
        ushort4 b4 = *(const ushort4*)&btbl[brow + kkb];
        acc[0] = bf2f(b4.x); acc[1] = bf2f(b4.y);
        acc[2] = bf2f(b4.z); acc[3] = bf2f(b4.w);
      }
      const size_t krow = ((size_t)bh * NKPAD + kb + 16 * t + lq) * 64 + 8 * lg;
#pragma unroll
      for (int ks = 0; ks < 2; ++ks) {
        bf16x8 ah = *(const bf16x8*)&Kh[krow + 32 * ks];
        bf16x8 al = *(const bf16x8*)&Kl[krow + 32 * ks];
        acc = MFMA16(ah, qbh[ks], acc);
        acc = MFMA16(ah, qbl[ks], acc);
        acc = MFMA16(al, qbh[ks], acc);
      }
      sv[t][0] = acc[0]; sv[t][1] = acc[1];
      sv[t][2] = acc[2]; sv[t][3] = acc[3];
    }

    // ---- mask + online softmax ----
    float cmax = NEGBIG;
#pragma unroll
    for (int t = 0; t < 4; ++t)
#pragma unroll
      for (int r = 0; r < 4; ++r) {
        int kl = 16 * t + 4 * lg + r;
        float s = ((m64 >> kl) & 1ull) ? sv[t][r] : NEGBIG;
        sv[t][r] = s;
        cmax = fmaxf(cmax, s);
      }
    cmax = fmaxf(cmax, __shfl_xor(cmax, 16));
    cmax = fmaxf(cmax, __shfl_xor(cmax, 32));
    float m_new = fmaxf(m_reg, cmax);
    float fx = __expf(m_reg - m_new);
    float csum = 0.f;
    float ev[4][4];
#pragma unroll
    for (int t = 0; t < 4; ++t)
#pragma unroll
      for (int r = 0; r < 4; ++r) {
        float e = __expf(sv[t][r] - m_new);
        ev[t][r] = e;
        csum += e;
      }
    csum += __shfl_xor(csum, 16);
    csum += __shfl_xor(csum, 32);
    l_reg = l_reg * fx + csum;
    m_reg = m_new;

    // ---- P -> per-wave LDS (swizzled) ----
#pragma unroll
    for (int t = 0; t < 4; ++t) {
      ushort4 ph, plo;
      split2(ev[t][0], ph.x, plo.x);
      split2(ev[t][1], ph.y, plo.y);
      split2(ev[t][2], ph.z, plo.z);
      split2(ev[t][3], ph.w, plo.w);
      int c = (16 * t + 4 * lg) ^ sw;
      *(ushort4*)&Ph[w][lq * 64 + c] = ph;
      *(ushort4*)&Pl[w][lq * 64 + c] = plo;
    }

    // ---- rescale accO ----
    float fxr[4];
#pragma unroll
    for (int r = 0; r < 4; ++r) fxr[r] = __shfl(fx, 4 * lg + r);
#pragma unroll
    for (int t = 0; t < 4; ++t) {
      accO[t][0] *= fxr[0]; accO[t][1] *= fxr[1];
      accO[t][2] *= fxr[2]; accO[t][3] *= fxr[3];
    }

    // ---- P fragments ----
    bf16x8 pah[2], pal[2];
#pragma unroll
    for (int ks = 0; ks < 2; ++ks) {
      int c = (8 * lg + 32 * ks) ^ sw;
      pah[ks] = *(const bf16x8*)&Ph[w][lq * 64 + c];
      pal[ks] = *(const bf16x8*)&Pl[w][lq * 64 + c];
    }

    // ---- O += P V (V frags direct from global) ----
#pragma unroll
    for (int t = 0; t < 4; ++t) {
      const size_t vrow = ((size_t)bh * 64 + 16 * t + lq) * NKPAD + kb + 8 * lg;
#pragma unroll
      for (int ks = 0; ks < 2; ++ks) {
        bf16x8 vh = *(const bf16x8*)&Vth[vrow + 32 * ks];
        bf16x8 vl = *(const bf16x8*)&Vtl[vrow + 32 * ks];
        accO[t] = MFMA16(pah[ks], vh, accO[t]);
        accO[t] = MFMA16(pal[ks], vh, accO[t]);
        accO[t] = MFMA16(pah[ks], vl, accO[t]);
      }
    }
  }

  float il = 1.f / l_reg;
  float ilr[4];
#pragma unroll
  for (int r = 0; r < 4; ++r) ilr[r] = __shfl(il, 4 * lg + r);
#pragma unroll
  for (int t = 0; t < 4; ++t)
#pragma unroll
    for (int r = 0; r < 4; ++r) {
      int gq2 = q0 + 16 * w + 4 * lg + r;
      if (gq2 < NN) {
        float v = accO[t][r] * ilr[r];
        u16 hi, lo;
        split2(v, hi, lo);
        size_t a = ((size_t)b * NN + gq2) * NC + h * 64 + 16 * t + lq;
        Oh[a] = hi;
        Ol[a] = lo;
      }
    }
}

// ---------------------------------------------------------------------------
// Projection GEMM, split-bf16 MFMA, LDS-free. Output fp32.
// ---------------------------------------------------------------------------
__global__ __launch_bounds__(256, 2) void proj_mfma_k(
    const u16* __restrict__ Ah, const u16* __restrict__ Al,
    const u16* __restrict__ Wh, const u16* __restrict__ Wl,
    const float* __restrict__ bias, float* __restrict__ out)
{
  const int tid = threadIdx.x;
  const int w = tid >> 6, l = tid & 63, lq = l & 15, lg = l >> 4;
  const int wm = (w >> 1) * 64, wn = (w & 1) * 64;
  const int m0 = blockIdx.x * 128 + wm;
  const int r0 = blockIdx.y * 128 + wn;

  f32x4 acc[4][4];
#pragma unroll
  for (int nt = 0; nt < 4; ++nt) {
    float bv = bias[r0 + 16 * nt + lq];
#pragma unroll
    for (int mt = 0; mt < 4; ++mt) acc[mt][nt] = (f32x4){bv, bv, bv, bv};
  }

  const size_t arow = (size_t)(m0 + lq) * 384 + 8 * lg;
  const size_t brow = (size_t)(r0 + lq) * 384 + 8 * lg;
  for (int k0 = 0; k0 < 384; k0 += 32) {
    bf16x8 ah[4], al[4], bh_[4], bl_[4];
#pragma unroll
    for (int mt = 0; mt < 4; ++mt) {
      ah[mt] = *(const bf16x8*)&Ah[arow + (size_t)(16 * mt) * 384 + k0];
      al[mt] = *(const bf16x8*)&Al[arow + (size_t)(16 * mt) * 384 + k0];
    }
#pragma unroll
    for (int nt = 0; nt < 4; ++nt) {
      bh_[nt] = *(const bf16x8*)&Wh[brow + (size_t)(16 * nt) * 384 + k0];
      bl_[nt] = *(const bf16x8*)&Wl[brow + (size_t)(16 * nt) * 384 + k0];
    }
#pragma unroll
    for (int mt = 0; mt < 4; ++mt)
#pragma unroll
      for (int nt = 0; nt < 4; ++nt) {
        acc[mt][nt] = MFMA16(ah[mt], bh_[nt], acc[mt][nt]);
        acc[mt][nt] = MFMA16(ah[mt], bl_[nt], acc[mt][nt]);
        acc[mt][nt] = MFMA16(al[mt], bh_[nt], acc[mt][nt]);
      }
  }

#pragma unroll
  for (int mt = 0; mt < 4; ++mt)
#pragma unroll
    for (int r = 0; r < 4; ++r) {
      int m = m0 + 16 * mt + 4 * lg + r;
      if (m >= MTOT) continue;
#pragma unroll
      for (int nt = 0; nt < 4; ++nt)
        out[(size_t)m * NC + r0 + 16 * nt + lq] = acc[mt][nt][r];
    }
}

// ---------------------------------------------------------------------------
extern "C" void kernel_launch(void* const* d_in, const int* in_sizes, int n_in,
                              void* d_out, int out_size, void* d_ws, size_t ws_size,
                              hipStream_t stream) {
  const float* x       = (const float*)d_in[0];
  const float* qkv_w   = (const float*)d_in[1];
  const float* qkv_b   = (const float*)d_in[2];
  const float* proj_w  = (const float*)d_in[3];
  const float* proj_b  = (const float*)d_in[4];
  const float* rel_pos = (const float*)d_in[5];
  const int*   rel_idx = (const int*)d_in[6];
  const int*   mask    = (const int*)d_in[7];
  const int*   patch   = (const int*)d_in[8];
  float* out = (float*)d_out;
  u16* W16 = (u16*)d_ws;

  unsigned* pmp = (unsigned*)(W16 + OFF_PM);
  u16* btblp = W16 + OFF_BT;

  split_inputs_k<<<4080, 256, 0, stream>>>(x, qkv_w, proj_w, W16);
  pack_mask_k<<<2308, 256, 0, stream>>>(mask, pmp);
  bias_build_k<<<dim3(NN, NH), 256, 0, stream>>>(rel_pos, rel_idx, patch, btblp);
  qkv_mfma_k<<<dim3(73, 9), 256, 0, stream>>>(
      W16 + OFF_XH, W16 + OFF_XL, W16 + OFF_WQH, W16 + OFF_WQL, qkv_b, W16);
  attn_k<<<dim3(10, NH, NB), 256, 0, stream>>>(
      W16 + OFF_QH, W16 + OFF_QL, W16 + OFF_KH, W16 + OFF_KL,
      W16 + OFF_VTH, W16 + OFF_VTL, btblp, pmp,
      W16 + OFF_XH, W16 + OFF_XL);
  proj_mfma_k<<<dim3(73, 3), 256, 0, stream>>>(
      W16 + OFF_XH, W16 + OFF_XL, W16 + OFF_WPH, W16 + OFF_WPL, proj_b, out);
}

// Round 5
// 181.494 us; speedup vs baseline: 1.8733x; 1.8733x over previous
//
#include <hip/hip_runtime.h>
#include <float.h>
#include <math.h>

#define NB 16
#define NN 577
#define NC 384
#define NH 6
#define ND 64
#define RPD2 2209
#define MTOT 9232
#define MPAD 9344
#define SCALE_ 0.125f
#define NEGBIG -3.0e38f
#define BSTRIDE 580
#define NKPAD 640

typedef __attribute__((ext_vector_type(8))) short bf16x8;
typedef __attribute__((ext_vector_type(4))) float f32x4;
typedef unsigned short u16;

#define MFMA16(a, b, c) __builtin_amdgcn_mfma_f32_16x16x32_bf16(a, b, c, 0, 0, 0)

// workspace offsets in u16 units
#define SQA 3932160ull                    // 96*640*64
#define OFF_QH 0ull
#define OFF_QL SQA
#define OFF_KH (2ull * SQA)
#define OFF_KL (3ull * SQA)
#define OFF_VTH (4ull * SQA)
#define OFF_VTL (5ull * SQA)
#define OFF_XH (6ull * SQA)               // aliased as Oh after qkv
#define OFF_XL (6ull * SQA + 3588096ull)  // aliased as Ol
#define OFF_WQH (6ull * SQA + 2ull * 3588096ull)
#define OFF_WQL (OFF_WQH + 442368ull)
#define OFF_WPH (OFF_WQL + 442368ull)
#define OFF_WPL (OFF_WPH + 147456ull)
#define OFF_BT  (OFF_WPL + 147456ull)
#define OFF_PM  (OFF_BT + 2007960ull)     // u32 region, 8B-aligned

static __device__ __forceinline__ u16 f2bf(float f) {
  unsigned u = __float_as_uint(f);
  u += 0x7fff + ((u >> 16) & 1);
  return (u16)(u >> 16);
}
static __device__ __forceinline__ float bf2f(u16 h) {
  return __uint_as_float((unsigned)h << 16);
}
static __device__ __forceinline__ void split2(float v, u16& hi, u16& lo) {
  hi = f2bf(v);
  lo = f2bf(v - bf2f(hi));
}
// async global->LDS, 16B per lane; LDS dest = wave-uniform base + lane*16
static __device__ __forceinline__ void gload16(const void* g, void* l) {
  __builtin_amdgcn_global_load_lds(
      (const __attribute__((address_space(1))) void*)g,
      (__attribute__((address_space(3))) void*)l, 16, 0, 0);
}

// ---------------------------------------------------------------------------
// Split fp32 inputs into bf16 hi/lo pairs (x padded to 9344 rows).
// ---------------------------------------------------------------------------
__global__ __launch_bounds__(256) void split_inputs_k(
    const float* __restrict__ x, const float* __restrict__ wq,
    const float* __restrict__ wp, u16* __restrict__ ws)
{
  const int q = blockIdx.x * 256 + threadIdx.x;
  float4 v = {0.f, 0.f, 0.f, 0.f};
  u16 *dh, *dl;
  if (q < 897024) {
    if (q < 886272) v = ((const float4*)x)[q];
    dh = ws + OFF_XH + 4ull * q;
    dl = ws + OFF_XL + 4ull * q;
  } else if (q < 1007616) {
    int t = q - 897024;
    v = ((const float4*)wq)[t];
    dh = ws + OFF_WQH + 4ull * t;
    dl = ws + OFF_WQL + 4ull * t;
  } else {
    int t = q - 1007616;
    v = ((const float4*)wp)[t];
    dh = ws + OFF_WPH + 4ull * t;
    dl = ws + OFF_WPL + 4ull * t;
  }
  ushort4 hh, ll;
  split2(v.x, hh.x, ll.x);
  split2(v.y, hh.y, ll.y);
  split2(v.z, hh.z, ll.z);
  split2(v.w, hh.w, ll.w);
  *(ushort4*)dh = hh;
  *(ushort4*)dl = ll;
}

// ---------------------------------------------------------------------------
// Pack mask int32 -> bitmask.
// ---------------------------------------------------------------------------
__global__ __launch_bounds__(256) void pack_mask_k(const int* __restrict__ mask,
                                                   unsigned* __restrict__ pm)
{
  const int wid = (blockIdx.x * 256 + threadIdx.x) >> 6;
  const int lane = threadIdx.x & 63;
  if (wid >= MTOT) return;
  const int* mr = mask + (size_t)wid * NN;
#pragma unroll
  for (int c = 0; c < 10; ++c) {
    int k = c * 64 + lane;
    int v = (k < NN) ? mr[k] : 0;
    unsigned long long bal = __ballot(v != 0);
    if (lane == 0) pm[wid * 20 + 2 * c] = (unsigned)bal;
    if (lane == 1) pm[wid * 20 + 2 * c + 1] = (unsigned)(bal >> 32);
  }
}

// ---------------------------------------------------------------------------
// Bias table: tbl[h][q][kk] = rel_pos[h][rel_idx[(q-1)*576 + kk-1]] bf16.
// ---------------------------------------------------------------------------
__global__ __launch_bounds__(256) void bias_build_k(
    const float* __restrict__ rel_pos, const int* __restrict__ rel_idx,
    const int* __restrict__ patch, u16* __restrict__ tbl)
{
  const int q = blockIdx.x;
  const int h = blockIdx.y;
  const int pa = *patch;
  u16* row = tbl + ((size_t)h * NN + q) * BSTRIDE;
  for (int kk = threadIdx.x; kk < BSTRIDE; kk += 256) {
    float v = 0.f;
    if (pa && q >= 1 && kk >= 1 && kk < NN)
      v = rel_pos[h * RPD2 + rel_idx[(q - 1) * 576 + (kk - 1)]];
    row[kk] = f2bf(v);
  }
}

// ---------------------------------------------------------------------------
// QKV GEMM, split-bf16 MFMA with LDS staging via global_load_lds.
// Tiles: A,B as [128][32] u16 (64B rows -> bank-friendly, no swizzle needed).
// Block 256 thr = 4 waves (2x2), wave tile 64x64, block tile 128x128, BK=32.
// ---------------------------------------------------------------------------
__global__ __launch_bounds__(256, 3) void qkv_mfma_k(
    const u16* __restrict__ Xh, const u16* __restrict__ Xl,
    const u16* __restrict__ Wh, const u16* __restrict__ Wl,
    const float* __restrict__ bias, u16* __restrict__ ws)
{
  __shared__ u16 Ash[4096], Asl[4096];   // [128][32]
  __shared__ u16 Bsh[4096], Bsl[4096];

  const int tid = threadIdx.x;
  const int w = tid >> 6, l = tid & 63, lq = l & 15, lg = l >> 4;
  const int wm = (w >> 1) * 64, wn = (w & 1) * 64;
  const int mb = blockIdx.x * 128;
  const int rb = blockIdx.y * 128;
  const int r0 = rb + wn;
  const int soff = (l >> 2) * 384 + (l & 3) * 8;   // staging per-lane src (u16)

  f32x4 acc[4][4];
#pragma unroll
  for (int nt = 0; nt < 4; ++nt) {
    float bv = bias[r0 + 16 * nt + lq];
#pragma unroll
    for (int mt = 0; mt < 4; ++mt) acc[mt][nt] = (f32x4){bv, bv, bv, bv};
  }

  for (int k0 = 0; k0 < 384; k0 += 32) {
    __syncthreads();
#pragma unroll
    for (int j = 0; j < 2; ++j) {
      const int tr = 32 * w + 16 * j;               // tile row base (16 rows/inst)
      const size_t ga = (size_t)(mb + tr) * 384 + k0 + soff;
      const size_t gb = (size_t)(rb + tr) * 384 + k0 + soff;
      gload16(&Xh[ga], &Ash[tr * 32]);
      gload16(&Xl[ga], &Asl[tr * 32]);
      gload16(&Wh[gb], &Bsh[tr * 32]);
      gload16(&Wl[gb], &Bsl[tr * 32]);
    }
    __syncthreads();

    bf16x8 bhf[4], blf[4];
#pragma unroll
    for (int nt = 0; nt < 4; ++nt) {
      bhf[nt] = *(const bf16x8*)&Bsh[(wn + 16 * nt + lq) * 32 + 8 * lg];
      blf[nt] = *(const bf16x8*)&Bsl[(wn + 16 * nt + lq) * 32 + 8 * lg];
    }
#pragma unroll
    for (int mt = 0; mt < 4; ++mt) {
      bf16x8 ah = *(const bf16x8*)&Ash[(wm + 16 * mt + lq) * 32 + 8 * lg];
      bf16x8 al = *(const bf16x8*)&Asl[(wm + 16 * mt + lq) * 32 + 8 * lg];
#pragma unroll
      for (int nt = 0; nt < 4; ++nt) {
        acc[mt][nt] = MFMA16(ah, bhf[nt], acc[mt][nt]);
        acc[mt][nt] = MFMA16(ah, blf[nt], acc[mt][nt]);
        acc[mt][nt] = MFMA16(al, bhf[nt], acc[mt][nt]);
      }
    }
  }

  const int comp = rb / 384;                 // 0=Q 1=K 2=V (block-uniform)
  const int h = ((rb % 384) + wn) >> 6;
#pragma unroll
  for (int mt = 0; mt < 4; ++mt)
#pragma unroll
    for (int r = 0; r < 4; ++r) {
      int m = mb + wm + 16 * mt + 4 * lg + r;
      if (m >= MTOT) continue;
      int bb = m / NN, nn = m - bb * NN;
      int bh = bb * NH + h;
#pragma unroll
      for (int nt = 0; nt < 4; ++nt) {
        int d = 16 * nt + lq;
        float v = acc[mt][nt][r];
        u16 hi, lo;
        if (comp == 0) {
          v *= SCALE_;
          split2(v, hi, lo);
          size_t a = ((size_t)bh * NKPAD + nn) * 64 + d;
          ws[OFF_QH + a] = hi;
          ws[OFF_QL + a] = lo;
        } else if (comp == 1) {
          split2(v, hi, lo);
          size_t a = ((size_t)bh * NKPAD + nn) * 64 + d;
          ws[OFF_KH + a] = hi;
          ws[OFF_KL + a] = lo;
        } else {
          split2(v, hi, lo);
          size_t a = ((size_t)bh * 64 + d) * NKPAD + nn;
          ws[OFF_VTH + a] = hi;
          ws[OFF_VTL + a] = lo;
        }
      }
    }
}

// ---------------------------------------------------------------------------
// Flash attention: LDS-staged K/V via global_load_lds with pre-swizzled
// source (XOR on 16B slots: LDS[row][s] = G[row][s ^ (row&7)]), read back
// with the matching XOR. Single buffer, 2 barriers/chunk. 48KB -> 3 blk/CU.
// ---------------------------------------------------------------------------
__global__ __launch_bounds__(256, 3) void attn_k(
    const u16* __restrict__ Qh, const u16* __restrict__ Ql,
    const u16* __restrict__ Kh, const u16* __restrict__ Kl,
    const u16* __restrict__ Vth, const u16* __restrict__ Vtl,
    const u16* __restrict__ btbl, const unsigned* __restrict__ pm,
    u16* __restrict__ Oh, u16* __restrict__ Ol)
{
  __shared__ u16 Kth[4096], Ktl[4096];   // [64 keys][64 d], swizzled
  __shared__ u16 Vsh[4096], Vsl[4096];   // [64 d][64 keys], swizzled
  __shared__ u16 Ph[4][1024], Pl[4][1024];

  const int tid = threadIdx.x;
  const int w = tid >> 6, l = tid & 63, lq = l & 15, lg = l >> 4;
  const int q0 = blockIdx.x * 64;
  const int h = blockIdx.y, b = blockIdx.z;
  const int bh = b * NH + h;
  const int qrow = q0 + 16 * w + lq;
  const int swz = (lq & 7) << 3;
  const int ln8 = l >> 3, lc8 = l & 7;
  const int koff = ln8 * 64 + ((lc8 ^ ln8) << 3);    // K tile per-lane src (u16)
  const int voff = ln8 * NKPAD + ((lc8 ^ ln8) << 3); // V tile per-lane src (u16)

  // persistent Q fragments
  const size_t qbase = ((size_t)bh * NKPAD + qrow) * 64 + 8 * lg;
  bf16x8 qbh[2], qbl[2];
  qbh[0] = *(const bf16x8*)&Qh[qbase];
  qbh[1] = *(const bf16x8*)&Qh[qbase + 32];
  qbl[0] = *(const bf16x8*)&Ql[qbase];
  qbl[1] = *(const bf16x8*)&Ql[qbase + 32];

  const bool qv = qrow < NN;
  const int gqc = qv ? qrow : NN - 1;
  const unsigned* pmrow = pm + ((size_t)b * NN + gqc) * 20;
  const size_t brow = ((size_t)h * NN + gqc) * BSTRIDE;

  float m_reg = NEGBIG, l_reg = 0.f;
  f32x4 accO[4] = {};

  for (int ch = 0; ch < 10; ++ch) {
    const int kb = ch * 64;
    __syncthreads();   // prior chunk's LDS reads done
    {
      const size_t kgb = ((size_t)bh * NKPAD + kb + 16 * w) * 64 + koff;
      const size_t vgb = ((size_t)bh * 64 + 16 * w) * NKPAD + kb + voff;
      gload16(&Kh[kgb],                 &Kth[(16 * w) * 64]);
      gload16(&Kh[kgb + 512],           &Kth[(16 * w + 8) * 64]);
      gload16(&Kl[kgb],                 &Ktl[(16 * w) * 64]);
      gload16(&Kl[kgb + 512],           &Ktl[(16 * w + 8) * 64]);
      gload16(&Vth[vgb],                &Vsh[(16 * w) * 64]);
      gload16(&Vth[vgb + 8 * NKPAD],    &Vsh[(16 * w + 8) * 64]);
      gload16(&Vtl[vgb],                &Vsl[(16 * w) * 64]);
      gload16(&Vtl[vgb + 8 * NKPAD],    &Vsl[(16 * w + 8) * 64]);
    }
    // independent global loads overlap the staging drain
    unsigned long long m64 = (unsigned long long)pmrow[2 * ch] |
                             ((unsigned long long)pmrow[2 * ch + 1] << 32);
    f32x4 cinit[4];
#pragma unroll
    for (int t = 0; t < 4; ++t) {
      cinit[t] = (f32x4){0.f, 0.f, 0.f, 0.f};
      int kkb = kb + 16 * t + 4 * lg;
      if (qv && kkb <= 576) {
        ushort4 b4 = *(const ushort4*)&btbl[brow + kkb];
        cinit[t][0] = bf2f(b4.x); cinit[t][1] = bf2f(b4.y);
        cinit[t][2] = bf2f(b4.z); cinit[t][3] = bf2f(b4.w);
      }
    }
    __syncthreads();   // K/V tiles ready (vmcnt drained by barrier)

    // ---- S^T = K*Q^T ----
    float sv[4][4];
#pragma unroll
    for (int t = 0; t < 4; ++t) {
      f32x4 acc = cinit[t];
      const int ar = (16 * t + lq) * 64;
#pragma unroll
      for (int ks = 0; ks < 2; ++ks) {
        const int c = (8 * lg + 32 * ks) ^ swz;
        bf16x8 ah = *(const bf16x8*)&Kth[ar + c];
        bf16x8 al = *(const bf16x8*)&Ktl[ar + c];
        acc = MFMA16(ah, qbh[ks], acc);
        acc = MFMA16(ah, qbl[ks], acc);
        acc = MFMA16(al, qbh[ks], acc);
      }
      sv[t][0] = acc[0]; sv[t][1] = acc[1];
      sv[t][2] = acc[2]; sv[t][3] = acc[3];
    }

    // ---- mask + online softmax (lane q = qrow) ----
    float cmax = NEGBIG;
#pragma unroll
    for (int t = 0; t < 4; ++t)
#pragma unroll
      for (int r = 0; r < 4; ++r) {
        int kl = 16 * t + 4 * lg + r;
        float s = ((m64 >> kl) & 1ull) ? sv[t][r] : NEGBIG;
        sv[t][r] = s;
        cmax = fmaxf(cmax, s);
      }
    cmax = fmaxf(cmax, __shfl_xor(cmax, 16));
    cmax = fmaxf(cmax, __shfl_xor(cmax, 32));
    float m_new = fmaxf(m_reg, cmax);
    float fx = __expf(m_reg - m_new);
    float csum = 0.f;
    float ev[4][4];
#pragma unroll
    for (int t = 0; t < 4; ++t)
#pragma unroll
      for (int r = 0; r < 4; ++r) {
        float e = __expf(sv[t][r] - m_new);
        ev[t][r] = e;
        csum += e;
      }
    csum += __shfl_xor(csum, 16);
    csum += __shfl_xor(csum, 32);
    l_reg = l_reg * fx + csum;
    m_reg = m_new;

    // ---- P -> per-wave LDS (swizzled) ----
#pragma unroll
    for (int t = 0; t < 4; ++t) {
      ushort4 ph, plo;
      split2(ev[t][0], ph.x, plo.x);
      split2(ev[t][1], ph.y, plo.y);
      split2(ev[t][2], ph.z, plo.z);
      split2(ev[t][3], ph.w, plo.w);
      int c = (16 * t + 4 * lg) ^ swz;
      *(ushort4*)&Ph[w][lq * 64 + c] = ph;
      *(ushort4*)&Pl[w][lq * 64 + c] = plo;
    }

    // ---- rescale accO ----
    float fxr[4];
#pragma unroll
    for (int r = 0; r < 4; ++r) fxr[r] = __shfl(fx, 4 * lg + r);
#pragma unroll
    for (int t = 0; t < 4; ++t) {
      accO[t][0] *= fxr[0]; accO[t][1] *= fxr[1];
      accO[t][2] *= fxr[2]; accO[t][3] *= fxr[3];
    }

    // ---- P fragments (wave-private, no barrier needed) ----
    bf16x8 pah[2], pal[2];
#pragma unroll
    for (int ks = 0; ks < 2; ++ks) {
      int c = (8 * lg + 32 * ks) ^ swz;
      pah[ks] = *(const bf16x8*)&Ph[w][lq * 64 + c];
      pal[ks] = *(const bf16x8*)&Pl[w][lq * 64 + c];
    }

    // ---- O += P V ----
#pragma unroll
    for (int t = 0; t < 4; ++t) {
      const int vr = (16 * t + lq) * 64;
#pragma unroll
      for (int ks = 0; ks < 2; ++ks) {
        const int c = (8 * lg + 32 * ks) ^ swz;
        bf16x8 vh = *(const bf16x8*)&Vsh[vr + c];
        bf16x8 vl = *(const bf16x8*)&Vsl[vr + c];
        accO[t] = MFMA16(pah[ks], vh, accO[t]);
        accO[t] = MFMA16(pal[ks], vh, accO[t]);
        accO[t] = MFMA16(pah[ks], vl, accO[t]);
      }
    }
  }

  float il = 1.f / l_reg;
  float ilr[4];
#pragma unroll
  for (int r = 0; r < 4; ++r) ilr[r] = __shfl(il, 4 * lg + r);
#pragma unroll
  for (int t = 0; t < 4; ++t)
#pragma unroll
    for (int r = 0; r < 4; ++r) {
      int gq2 = q0 + 16 * w + 4 * lg + r;
      if (gq2 < NN) {
        float v = accO[t][r] * ilr[r];
        u16 hi, lo;
        split2(v, hi, lo);
        size_t a = ((size_t)b * NN + gq2) * NC + h * 64 + 16 * t + lq;
        Oh[a] = hi;
        Ol[a] = lo;
      }
    }
}

// ---------------------------------------------------------------------------
// Projection GEMM, split-bf16 MFMA with LDS staging. Output fp32.
// ---------------------------------------------------------------------------
__global__ __launch_bounds__(256, 3) void proj_mfma_k(
    const u16* __restrict__ Ah, const u16* __restrict__ Al,
    const u16* __restrict__ Wh, const u16* __restrict__ Wl,
    const float* __restrict__ bias, float* __restrict__ out)
{
  __shared__ u16 Ash[4096], Asl[4096];
  __shared__ u16 Bsh[4096], Bsl[4096];

  const int tid = threadIdx.x;
  const int w = tid >> 6, l = tid & 63, lq = l & 15, lg = l >> 4;
  const int wm = (w >> 1) * 64, wn = (w & 1) * 64;
  const int mb = blockIdx.x * 128;
  const int rb = blockIdx.y * 128;
  const int r0 = rb + wn;
  const int soff = (l >> 2) * 384 + (l & 3) * 8;

  f32x4 acc[4][4];
#pragma unroll
  for (int nt = 0; nt < 4; ++nt) {
    float bv = bias[r0 + 16 * nt + lq];
#pragma unroll
    for (int mt = 0; mt < 4; ++mt) acc[mt][nt] = (f32x4){bv, bv, bv, bv};
  }

  for (int k0 = 0; k0 < 384; k0 += 32) {
    __syncthreads();
#pragma unroll
    for (int j = 0; j < 2; ++j) {
      const int tr = 32 * w + 16 * j;
      const size_t ga = (size_t)(mb + tr) * 384 + k0 + soff;
      const size_t gb = (size_t)(rb + tr) * 384 + k0 + soff;
      gload16(&Ah[ga], &Ash[tr * 32]);
      gload16(&Al[ga], &Asl[tr * 32]);
      gload16(&Wh[gb], &Bsh[tr * 32]);
      gload16(&Wl[gb], &Bsl[tr * 32]);
    }
    __syncthreads();

    bf16x8 bhf[4], blf[4];
#pragma unroll
    for (int nt = 0; nt < 4; ++nt) {
      bhf[nt] = *(const bf16x8*)&Bsh[(wn + 16 * nt + lq) * 32 + 8 * lg];
      blf[nt] = *(const bf16x8*)&Bsl[(wn + 16 * nt + lq) * 32 + 8 * lg];
    }
#pragma unroll
    for (int mt = 0; mt < 4; ++mt) {
      bf16x8 ah = *(const bf16x8*)&Ash[(wm + 16 * mt + lq) * 32 + 8 * lg];
      bf16x8 al = *(const bf16x8*)&Asl[(wm + 16 * mt + lq) * 32 + 8 * lg];
#pragma unroll
      for (int nt = 0; nt < 4; ++nt) {
        acc[mt][nt] = MFMA16(ah, bhf[nt], acc[mt][nt]);
        acc[mt][nt] = MFMA16(ah, blf[nt], acc[mt][nt]);
        acc[mt][nt] = MFMA16(al, bhf[nt], acc[mt][nt]);
      }
    }
  }

#pragma unroll
  for (int mt = 0; mt < 4; ++mt)
#pragma unroll
    for (int r = 0; r < 4; ++r) {
      int m = mb + wm + 16 * mt + 4 * lg + r;
      if (m >= MTOT) continue;
#pragma unroll
      for (int nt = 0; nt < 4; ++nt)
        out[(size_t)m * NC + r0 + 16 * nt + lq] = acc[mt][nt][r];
    }
}

// ---------------------------------------------------------------------------
extern "C" void kernel_launch(void* const* d_in, const int* in_sizes, int n_in,
                              void* d_out, int out_size, void* d_ws, size_t ws_size,
                              hipStream_t stream) {
  const float* x       = (const float*)d_in[0];
  const float* qkv_w   = (const float*)d_in[1];
  const float* qkv_b   = (const float*)d_in[2];
  const float* proj_w  = (const float*)d_in[3];
  const float* proj_b  = (const float*)d_in[4];
  const float* rel_pos = (const float*)d_in[5];
  const int*   rel_idx = (const int*)d_in[6];
  const int*   mask    = (const int*)d_in[7];
  const int*   patch   = (const int*)d_in[8];
  float* out = (float*)d_out;
  u16* W16 = (u16*)d_ws;

  unsigned* pmp = (unsigned*)(W16 + OFF_PM);
  u16* btblp = W16 + OFF_BT;

  split_inputs_k<<<4080, 256, 0, stream>>>(x, qkv_w, proj_w, W16);
  pack_mask_k<<<2308, 256, 0, stream>>>(mask, pmp);
  bias_build_k<<<dim3(NN, NH), 256, 0, stream>>>(rel_pos, rel_idx, patch, btblp);
  qkv_mfma_k<<<dim3(73, 9), 256, 0, stream>>>(
      W16 + OFF_XH, W16 + OFF_XL, W16 + OFF_WQH, W16 + OFF_WQL, qkv_b, W16);
  attn_k<<<dim3(10, NH, NB), 256, 0, stream>>>(
      W16 + OFF_QH, W16 + OFF_QL, W16 + OFF_KH, W16 + OFF_KL,
      W16 + OFF_VTH, W16 + OFF_VTL, btblp, pmp,
      W16 + OFF_XH, W16 + OFF_XL);
  proj_mfma_k<<<dim3(73, 3), 256, 0, stream>>>(
      W16 + OFF_XH, W16 + OFF_XL, W16 + OFF_WPH, W16 + OFF_WPL, proj_b, out);
}